// Round 1
// baseline (330.641 us; speedup 1.0000x reference)
//
#include <hip/hip_runtime.h>

// 4-bit ripple-borrow subtractor, one thread per row.
// A,B: (N,4) float32 with values in {0.0, 1.0}.
// Out: [ diffs (N,4) | borrow (N,1) ] flat float32.
// Index 3 is the LSB (reference loops i = 3..0).
__global__ __launch_bounds__(256) void Subtractor4Bit_kernel(
    const float4* __restrict__ A,
    const float4* __restrict__ B,
    float4* __restrict__ res,
    float* __restrict__ borrow_out,
    int n_rows)
{
    int i = blockIdx.x * blockDim.x + threadIdx.x;
    if (i >= n_rows) return;

    float4 a = A[i];
    float4 b = B[i];

    // Convert to 0/1 ints (inputs are exactly 0.0f or 1.0f).
    int a0 = (a.x != 0.0f), a1 = (a.y != 0.0f), a2 = (a.z != 0.0f), a3 = (a.w != 0.0f);
    int b0 = (b.x != 0.0f), b1 = (b.y != 0.0f), b2 = (b.z != 0.0f), b3 = (b.w != 0.0f);

    int bor = 0;

    // i = 3 (LSB)
    int d3 = a3 ^ b3 ^ bor;
    int na = 1 - a3;
    bor = (na & b3) | (na & bor) | (b3 & bor);
    // i = 2
    int d2 = a2 ^ b2 ^ bor;
    na = 1 - a2;
    bor = (na & b2) | (na & bor) | (b2 & bor);
    // i = 1
    int d1 = a1 ^ b1 ^ bor;
    na = 1 - a1;
    bor = (na & b1) | (na & bor) | (b1 & bor);
    // i = 0 (MSB)
    int d0 = a0 ^ b0 ^ bor;
    na = 1 - a0;
    bor = (na & b0) | (na & bor) | (b0 & bor);

    float4 r;
    r.x = (float)d0;
    r.y = (float)d1;
    r.z = (float)d2;
    r.w = (float)d3;
    res[i] = r;
    borrow_out[i] = (float)bor;
}

extern "C" void kernel_launch(void* const* d_in, const int* in_sizes, int n_in,
                              void* d_out, int out_size, void* d_ws, size_t ws_size,
                              hipStream_t stream)
{
    const float4* A = (const float4*)d_in[0];
    const float4* B = (const float4*)d_in[1];
    float* out = (float*)d_out;

    int n_rows = in_sizes[0] / 4;            // (N,4) -> N rows
    float4* res = (float4*)out;              // first 4*N floats: diffs
    float* borrow = out + (size_t)n_rows * 4; // last N floats: borrow

    int block = 256;
    int grid = (n_rows + block - 1) / block;
    Subtractor4Bit_kernel<<<grid, block, 0, stream>>>(A, B, res, borrow, n_rows);
}